// Round 1
// baseline (318.625 us; speedup 1.0000x reference)
//
#include <hip/hip_runtime.h>
#include <hip/hip_fp16.h>

// equivariant_encoder: only the l=1 path reaches the output.
// enc[g,v,m] = sum_u agg(seg_sum(t[i,u]*sqrt3*pos[i,m]*0.125))[g,u,m] * Lcomb[u,v]
//   t[i] = MLP(node i) @ (W_m2 @ w_tp1) + b_m2 @ w_tp1
//   Lcomb = (L1o @ L_out) / 64
// g0/g2/c0/c2/w_tp0/w_tp2/L0/L2e are dead code in the reference.

__device__ __forceinline__ float gelu_tanh(float x) {
    // jax.nn.gelu default (approximate=True): 0.5x(1+tanh(0.79788456(x+0.044715x^3)))
    float y = 0.7978845608028654f * (x + 0.044715f * x * x * x);
    float e = __expf(2.0f * y);
    return x - x / (e + 1.0f);   // == 0.5x(1+tanh(y))
}

__device__ __forceinline__ void storeT(float* p, float v) { *p = v; }
__device__ __forceinline__ void storeT(__half* p, float v) { *p = __float2half(v); }
__device__ __forceinline__ float loadT(const float* p) { return *p; }
__device__ __forceinline__ float loadT(const __half* p) { return __half2float(*p); }

// K-input, 64-output dense layer; x comes from column-private LDS scratch.
template<int K>
__device__ __forceinline__ void layer_from_lds(const float (*xs)[128], int tid,
                                               const float* __restrict__ W,
                                               const float* __restrict__ b,
                                               float acc[64]) {
    #pragma unroll
    for (int c = 0; c < 64; ++c) acc[c] = b[c];
    #pragma unroll 2
    for (int k = 0; k < K; ++k) {
        float xk = xs[k][tid];
        const float* w = W + (size_t)k * 64;
        #pragma unroll
        for (int c = 0; c < 64; ++c) acc[c] = fmaf(xk, w[c], acc[c]);
    }
}

// ---------------- K0: fold weights ----------------
__global__ void fold_kernel(const float* __restrict__ W_m2, const float* __restrict__ b_m2,
                            const float* __restrict__ w_tp1,
                            const float* __restrict__ L1o, const float* __restrict__ L_out,
                            float* __restrict__ Wc, float* __restrict__ bc,
                            float* __restrict__ Lcomb) {
    int tid = threadIdx.x;
    for (int idx = tid; idx < 64 * 64; idx += 256) {
        int a = idx >> 6, b = idx & 63;
        float s = 0.f;
        for (int k = 0; k < 64; ++k) s = fmaf(W_m2[a * 64 + k], w_tp1[k * 64 + b], s);
        Wc[idx] = s;
    }
    for (int b = tid; b < 64; b += 256) {
        float s = 0.f;
        for (int k = 0; k < 64; ++k) s = fmaf(b_m2[k], w_tp1[k * 64 + b], s);
        bc[b] = s;
    }
    for (int idx = tid; idx < 64 * 85; idx += 256) {
        int u = idx / 85, v = idx % 85;
        float s = 0.f;
        for (int k = 0; k < 64; ++k) s = fmaf(L1o[u * 64 + k], L_out[k * 85 + v], s);
        Lcomb[idx] = 0.015625f * s;   // 1/64 = 0.125 * 0.125
    }
}

// ---------------- K0b: segment boundaries from sorted batch ----------------
__global__ void seg_kernel(const int* __restrict__ batch, int* __restrict__ seg,
                           int n, int G) {
    int i = blockIdx.x * 256 + threadIdx.x;
    if (i >= n) return;
    int bi = batch[i];
    int bprev = (i == 0) ? -1 : batch[i - 1];
    for (int g = bprev + 1; g <= bi; ++g) seg[g] = i;       // seg[g] = first idx with batch >= g
    if (i == n - 1) {
        for (int g = bi + 1; g <= G; ++g) seg[g] = n;
    }
}

// ---------------- K1: per-node MLP -> t[64] ----------------
template<typename TS>
__global__ __launch_bounds__(128)
void node_kernel(const float* __restrict__ pos, const int* __restrict__ z,
                 const float* __restrict__ node_table,
                 const float* __restrict__ W_rbf0, const float* __restrict__ b_rbf0,
                 const float* __restrict__ W_rbf1, const float* __restrict__ b_rbf1,
                 const float* __restrict__ W_m0, const float* __restrict__ b_m0,
                 const float* __restrict__ W_m1, const float* __restrict__ b_m1,
                 const float* __restrict__ Wc, const float* __restrict__ bc,
                 TS* __restrict__ Tout, int n) {
    __shared__ float xs[64][128];   // column-private per-thread scratch (no barriers needed)
    const int tid = threadIdx.x;
    const int i = blockIdx.x * 128 + tid;
    const bool valid = i < n;
    const int ii = valid ? i : (n - 1);

    float px = pos[3 * ii + 0], py = pos[3 * ii + 1], pz = pos[3 * ii + 2];
    float dist = sqrtf(px * px + py * py + pz * pz);

    // rbf: 32 gaussians, offsets j/31, coeff = -0.5/(1/31)^2 = -480.5
    const float step = 1.0f / 31.0f;
    #pragma unroll
    for (int j = 0; j < 32; ++j) {
        float d = dist - (float)j * step;
        xs[j][tid] = __expf(-480.5f * d * d);
    }

    float acc[64];
    // r = gelu(rbf @ W_rbf0 + b_rbf0)
    layer_from_lds<32>(xs, tid, W_rbf0, b_rbf0, acc);
    #pragma unroll
    for (int c = 0; c < 64; ++c) xs[c][tid] = gelu_tanh(acc[c]);
    // r = r @ W_rbf1 + b_rbf1  (no activation)
    layer_from_lds<64>(xs, tid, W_rbf1, b_rbf1, acc);
    #pragma unroll
    for (int c = 0; c < 64; ++c) xs[c][tid] = acc[c];
    // h = gelu([r | table] @ W_m0 + b_m0): K=96 split 64 (LDS) + 32 (table, per-lane)
    layer_from_lds<64>(xs, tid, W_m0, b_m0, acc);
    {
        const int zi = z[ii];
        const float* tb = node_table + (size_t)zi * 32;
        #pragma unroll 2
        for (int k = 0; k < 32; ++k) {
            float xk = tb[k];
            const float* w = W_m0 + (size_t)(64 + k) * 64;
            #pragma unroll
            for (int c = 0; c < 64; ++c) acc[c] = fmaf(xk, w[c], acc[c]);
        }
    }
    #pragma unroll
    for (int c = 0; c < 64; ++c) xs[c][tid] = gelu_tanh(acc[c]);
    // h = gelu(h @ W_m1 + b_m1)
    layer_from_lds<64>(xs, tid, W_m1, b_m1, acc);
    #pragma unroll
    for (int c = 0; c < 64; ++c) xs[c][tid] = gelu_tanh(acc[c]);
    // t = h @ Wc + bc   (Wc = W_m2 @ w_tp1 folded)
    layer_from_lds<64>(xs, tid, Wc, bc, acc);

    if (valid) {
        TS* o = Tout + (size_t)i * 64;
        #pragma unroll
        for (int c = 0; c < 64; ++c) storeT(o + c, acc[c]);
    }
}

// ---------------- K2: per-graph reduction + Lcomb matmul ----------------
template<typename TS>
__global__ __launch_bounds__(256)
void graph_kernel(const TS* __restrict__ Tin, const float* __restrict__ pos,
                  const int* __restrict__ seg, const float* __restrict__ Lcomb,
                  float* __restrict__ out, int G) {
    __shared__ float g1s[4][64][3];
    const int lane = threadIdx.x & 63;
    const int wid = threadIdx.x >> 6;
    const int g = blockIdx.x * 4 + wid;   // grid = G/4 exactly (G=8192)

    const int s = seg[g], e = seg[g + 1];
    float a0 = 0.f, a1 = 0.f, a2 = 0.f;
    for (int nn = s; nn < e; ++nn) {
        float t = loadT(Tin + (size_t)nn * 64 + lane);   // coalesced 256B/wave
        float qx = pos[3 * nn + 0], qy = pos[3 * nn + 1], qz = pos[3 * nn + 2]; // uniform
        a0 = fmaf(t, qx, a0);
        a1 = fmaf(t, qy, a1);
        a2 = fmaf(t, qz, a2);
    }
    float cnt = (float)((e - s) > 0 ? (e - s) : 1);
    // sqrt(3) (sh1) * 0.125 (tp inv) * agg scale (1 + 1/cnt)
    float sc = 1.7320508075688772f * 0.125f * (1.0f + 1.0f / cnt);
    g1s[wid][lane][0] = a0 * sc;
    g1s[wid][lane][1] = a1 * sc;
    g1s[wid][lane][2] = a2 * sc;
    __syncthreads();

    float o0 = 0.f, o1 = 0.f, o2 = 0.f, p0 = 0.f, p1 = 0.f, p2 = 0.f;
    const int v2 = 64 + lane;
    for (int u = 0; u < 64; ++u) {
        float b0 = g1s[wid][u][0], b1 = g1s[wid][u][1], b2 = g1s[wid][u][2]; // LDS broadcast
        float l0 = Lcomb[u * 85 + lane];
        o0 = fmaf(b0, l0, o0); o1 = fmaf(b1, l0, o1); o2 = fmaf(b2, l0, o2);
        if (lane < 21) {
            float l1 = Lcomb[u * 85 + v2];
            p0 = fmaf(b0, l1, p0); p1 = fmaf(b1, l1, p1); p2 = fmaf(b2, l1, p2);
        }
    }
    float* og = out + (size_t)g * 255;
    og[3 * lane + 0] = o0; og[3 * lane + 1] = o1; og[3 * lane + 2] = o2;
    if (lane < 21) {
        og[3 * v2 + 0] = p0; og[3 * v2 + 1] = p1; og[3 * v2 + 2] = p2;
    }
}

extern "C" void kernel_launch(void* const* d_in, const int* in_sizes, int n_in,
                              void* d_out, int out_size, void* d_ws, size_t ws_size,
                              hipStream_t stream) {
    const float* pos        = (const float*)d_in[0];
    const int*   z          = (const int*)d_in[1];
    const int*   batch      = (const int*)d_in[2];
    const float* node_table = (const float*)d_in[3];
    const float* W_rbf0     = (const float*)d_in[4];
    const float* b_rbf0     = (const float*)d_in[5];
    const float* W_rbf1     = (const float*)d_in[6];
    const float* b_rbf1     = (const float*)d_in[7];
    const float* W_m0       = (const float*)d_in[8];
    const float* b_m0       = (const float*)d_in[9];
    const float* W_m1       = (const float*)d_in[10];
    const float* b_m1       = (const float*)d_in[11];
    const float* W_m2       = (const float*)d_in[12];
    const float* b_m2       = (const float*)d_in[13];
    const float* w_tp1      = (const float*)d_in[15];
    const float* L1o        = (const float*)d_in[18];
    const float* L_out      = (const float*)d_in[20];
    float* out = (float*)d_out;

    const int N = in_sizes[0] / 3;       // 200000
    const int G = out_size / 255;        // 8192

    // workspace layout
    char* ws = (char*)d_ws;
    float* Wc    = (float*)(ws + 0);         // 64*64*4   = 16384
    float* bc    = (float*)(ws + 16384);     // 64*4      = 256
    float* Lcomb = (float*)(ws + 16640);     // 64*85*4   = 21760 -> ends 38400
    int*   seg   = (int*)(ws + 38400);       // (G+1)*4   = 32772 -> ends 71172
    const size_t toff = 71424;               // 256-aligned
    const size_t needF32 = toff + (size_t)N * 64 * sizeof(float);
    const bool useF32 = ws_size >= needF32;

    fold_kernel<<<1, 256, 0, stream>>>(W_m2, b_m2, w_tp1, L1o, L_out, Wc, bc, Lcomb);
    seg_kernel<<<(N + 255) / 256, 256, 0, stream>>>(batch, seg, N, G);

    if (useF32) {
        float* T = (float*)(ws + toff);
        node_kernel<float><<<(N + 127) / 128, 128, 0, stream>>>(
            pos, z, node_table, W_rbf0, b_rbf0, W_rbf1, b_rbf1,
            W_m0, b_m0, W_m1, b_m1, Wc, bc, T, N);
        graph_kernel<float><<<G / 4, 256, 0, stream>>>(T, pos, seg, Lcomb, out, G);
    } else {
        __half* T = (__half*)(ws + toff);
        node_kernel<__half><<<(N + 127) / 128, 128, 0, stream>>>(
            pos, z, node_table, W_rbf0, b_rbf0, W_rbf1, b_rbf1,
            W_m0, b_m0, W_m1, b_m1, Wc, bc, T, N);
        graph_kernel<__half><<<G / 4, 256, 0, stream>>>(T, pos, seg, Lcomb, out, G);
    }
}

// Round 2
// 97.266 us; speedup vs baseline: 3.2758x; 3.2758x over previous
//
#include <hip/hip_runtime.h>

// Only the l=1 path reaches the output (g0/g2/c0/c2/w_tp0/w_tp2/L0/L2e are dead).
// t[i] = MLP(node i) @ (W_m2 @ w_tp1) + b_m2 @ w_tp1 ; enc = agg(segsum(t x sqrt3*pos))/... @ (L1o@L_out)/64
// Node MLP runs on MFMA (bf16), with weights split hi+lo bf16 (error ~ eps^2 ~= f32).

typedef __attribute__((ext_vector_type(8))) short bf16x8;
typedef __attribute__((ext_vector_type(4))) float f32x4;
typedef unsigned short ushort_t;

__device__ __forceinline__ unsigned short f2bf(float x) {
    unsigned u = __float_as_uint(x);
    u += 0x7fff + ((u >> 16) & 1);          // round-to-nearest-even
    return (unsigned short)(u >> 16);
}
__device__ __forceinline__ float bf2f(unsigned short h) {
    return __uint_as_float(((unsigned)h) << 16);
}

__device__ __forceinline__ float gelu_tanh(float x) {
    float y = 0.7978845608028654f * (x + 0.044715f * x * x * x);
    float e = __expf(2.0f * y);
    return x - x / (e + 1.0f);               // == 0.5x(1+tanh(y))
}

// ---------------- fold1: Wc = W_m2@w_tp1, bc, Lcomb = (L1o@L_out)/64 ----------------
__global__ void fold1_kernel(const float* __restrict__ W_m2, const float* __restrict__ b_m2,
                             const float* __restrict__ w_tp1,
                             const float* __restrict__ L1o, const float* __restrict__ L_out,
                             float* __restrict__ Wc, float* __restrict__ bc,
                             float* __restrict__ Lcomb) {
    int idx = blockIdx.x * 256 + threadIdx.x;
    const int total = 4096 + 64 + 5440;
    for (; idx < total; idx += gridDim.x * 256) {
        if (idx < 4096) {
            int a = idx >> 6, b = idx & 63;
            float s = 0.f;
            for (int k = 0; k < 64; ++k) s = fmaf(W_m2[a * 64 + k], w_tp1[k * 64 + b], s);
            Wc[idx] = s;                       // Wc[k_in][n_out]
        } else if (idx < 4160) {
            int b = idx - 4096;
            float s = 0.f;
            for (int k = 0; k < 64; ++k) s = fmaf(b_m2[k], w_tp1[k * 64 + b], s);
            bc[b] = s;
        } else {
            int i2 = idx - 4160;
            int u = i2 / 85, v = i2 % 85;
            float s = 0.f;
            for (int k = 0; k < 64; ++k) s = fmaf(L1o[u * 64 + k], L_out[k * 85 + v], s);
            Lcomb[i2] = 0.015625f * s;         // * (1/8)^2
        }
    }
}

// ---------------- fold2: transpose + hi/lo split all weights to bf16 ----------------
__device__ __forceinline__ void split_one(const float* __restrict__ src, int K,
                                          ushort_t* __restrict__ dh, ushort_t* __restrict__ dl,
                                          int g0, int gsz) {
    for (int i = g0; i < 64 * K; i += gsz) {
        int n = i / K, k = i - n * K;
        float w = src[k * 64 + n];            // src is [K][64] row-major
        unsigned short h = f2bf(w);
        dh[i] = h;
        dl[i] = f2bf(w - bf2f(h));
    }
}
__global__ void fold2_kernel(const float* __restrict__ W_rbf0, const float* __restrict__ W_rbf1,
                             const float* __restrict__ W_m0, const float* __restrict__ W_m1,
                             const float* __restrict__ Wc, ushort_t* __restrict__ wb) {
    const int gsz = gridDim.x * 256;
    const int g0 = blockIdx.x * 256 + threadIdx.x;
    split_one(W_rbf0, 32, wb + 0,     wb + 2048,  g0, gsz);
    split_one(W_rbf1, 64, wb + 4096,  wb + 8192,  g0, gsz);
    split_one(W_m0,   96, wb + 12288, wb + 18432, g0, gsz);
    split_one(W_m1,   64, wb + 24576, wb + 28672, g0, gsz);
    split_one(Wc,     64, wb + 32768, wb + 36864, g0, gsz);
}

// ---------------- seg boundaries from sorted batch ----------------
__global__ void seg_kernel(const int* __restrict__ batch, int* __restrict__ seg,
                           int n, int G) {
    int i = blockIdx.x * 256 + threadIdx.x;
    if (i >= n) return;
    int bi = batch[i];
    int bprev = (i == 0) ? -1 : batch[i - 1];
    for (int g = bprev + 1; g <= bi; ++g) seg[g] = i;
    if (i == n - 1) {
        for (int g = bi + 1; g <= G; ++g) seg[g] = n;
    }
}

// ---------------- MFMA node MLP ----------------
#define S0 104   // buf0 row stride (ushorts): 96 data + 8 pad
#define S1 72    // buf1 row stride: 64 + 8

__device__ __forceinline__ void store4(float* p, f32x4 v) {
    *(float4*)p = make_float4(v[0], v[1], v[2], v[3]);
}
__device__ __forceinline__ void store4(ushort_t* p, f32x4 v) {
    ushort4 u; u.x = f2bf(v[0]); u.y = f2bf(v[1]); u.z = f2bf(v[2]); u.w = f2bf(v[3]);
    *(ushort4*)p = u;
}

// One dense layer on MFMA. ACT: 0 = none->LDS, 1 = gelu->LDS, 2 = none->global T.
// Wave (wm,wn): features [32wm,32wm+32), nodes [64wn,64wn+64).
template<int K, int ACT, typename TS>
__device__ __forceinline__ void mfma_layer(
    const ushort_t* __restrict__ Wh, const ushort_t* __restrict__ Wl,
    const float* __restrict__ bias,
    const ushort_t* __restrict__ bin, int sin,
    ushort_t* __restrict__ bout, int sout,
    TS* __restrict__ Tout, int nodebase, int Nvalid,
    int wm, int wn, int lrow, int lcol)
{
    f32x4 acc[2][4];
    #pragma unroll
    for (int m = 0; m < 2; ++m) {
        const int f0 = wm * 32 + m * 16 + lrow * 4;
        float4 bv = *(const float4*)(bias + f0);
        #pragma unroll
        for (int n = 0; n < 4; ++n) { acc[m][n][0] = bv.x; acc[m][n][1] = bv.y; acc[m][n][2] = bv.z; acc[m][n][3] = bv.w; }
    }
    #pragma unroll
    for (int kt = 0; kt < K / 32; ++kt) {
        const int kof = kt * 32 + lrow * 8;
        bf16x8 ah[2], al[2], bb[4];
        #pragma unroll
        for (int m = 0; m < 2; ++m) {
            const int feat = wm * 32 + m * 16 + lcol;
            ah[m] = *(const bf16x8*)(Wh + feat * K + kof);
            al[m] = *(const bf16x8*)(Wl + feat * K + kof);
        }
        #pragma unroll
        for (int n = 0; n < 4; ++n) {
            const int node = wn * 64 + n * 16 + lcol;
            bb[n] = *(const bf16x8*)(bin + node * sin + kof);
        }
        #pragma unroll
        for (int m = 0; m < 2; ++m)
            #pragma unroll
            for (int n = 0; n < 4; ++n) {
                acc[m][n] = __builtin_amdgcn_mfma_f32_16x16x32_bf16(ah[m], bb[n], acc[m][n], 0, 0, 0);
                acc[m][n] = __builtin_amdgcn_mfma_f32_16x16x32_bf16(al[m], bb[n], acc[m][n], 0, 0, 0);
            }
    }
    #pragma unroll
    for (int m = 0; m < 2; ++m) {
        const int f0 = wm * 32 + m * 16 + lrow * 4;
        #pragma unroll
        for (int n = 0; n < 4; ++n) {
            const int node = wn * 64 + n * 16 + lcol;
            f32x4 v = acc[m][n];
            if (ACT == 1) {
                #pragma unroll
                for (int r = 0; r < 4; ++r) v[r] = gelu_tanh(v[r]);
            }
            if (ACT == 2) {
                if (nodebase + node < Nvalid)
                    store4(Tout + (size_t)(nodebase + node) * 64 + f0, v);
            } else {
                store4(bout + node * sout + f0, v);
            }
        }
    }
}

template<typename TS>
__global__ __launch_bounds__(256, 3)
void node_mfma_kernel(const float* __restrict__ pos, const int* __restrict__ z,
                      const float* __restrict__ node_table,
                      const ushort_t* __restrict__ wb,
                      const float* __restrict__ b_rbf0, const float* __restrict__ b_rbf1,
                      const float* __restrict__ b_m0, const float* __restrict__ b_m1,
                      const float* __restrict__ bc,
                      TS* __restrict__ Tout, int N)
{
    __shared__ ushort_t buf0[128 * S0];
    __shared__ ushort_t buf1[128 * S1];
    const int tid = threadIdx.x;
    const int nodebase = blockIdx.x * 128;

    // stage rbf (cols 0..31) + table (cols 64..95) into buf0
    {
        const int nl = tid >> 1;             // local node 0..127
        const int half = tid & 1;            // 16-column half
        int gn = nodebase + nl;
        if (gn > N - 1) gn = N - 1;
        const float px = pos[3 * gn], py = pos[3 * gn + 1], pz = pos[3 * gn + 2];
        const float dist = sqrtf(px * px + py * py + pz * pz);
        ushort_t w[16];
        #pragma unroll
        for (int j = 0; j < 16; ++j) {
            float d = dist - (float)(16 * half + j) * (1.0f / 31.0f);
            w[j] = f2bf(__expf(-480.5f * d * d));
        }
        #pragma unroll
        for (int j = 0; j < 4; ++j)
            *(ushort4*)&buf0[nl * S0 + half * 16 + 4 * j] = *(ushort4*)&w[4 * j];
        const float* tb = node_table + (size_t)z[gn] * 32 + half * 16;
        #pragma unroll
        for (int j = 0; j < 16; ++j) w[j] = f2bf(tb[j]);
        #pragma unroll
        for (int j = 0; j < 4; ++j)
            *(ushort4*)&buf0[nl * S0 + 64 + half * 16 + 4 * j] = *(ushort4*)&w[4 * j];
    }
    __syncthreads();

    const int wid = tid >> 6, lane = tid & 63;
    const int wm = wid >> 1, wn = wid & 1;
    const int lrow = lane >> 4, lcol = lane & 15;

    // L1: gelu(rbf @ W_rbf0 + b)        buf0[0:32] -> buf1
    mfma_layer<32, 1>(wb + 0, wb + 2048, b_rbf0, buf0, S0, buf1, S1,
                      (TS*)nullptr, 0, 0, wm, wn, lrow, lcol);
    __syncthreads();
    // L2: r @ W_rbf1 + b (no act)       buf1 -> buf0[0:64]   (table stays at 64:96)
    mfma_layer<64, 0>(wb + 4096, wb + 8192, b_rbf1, buf1, S1, buf0, S0,
                      (TS*)nullptr, 0, 0, wm, wn, lrow, lcol);
    __syncthreads();
    // L3: gelu([r|table] @ W_m0 + b)    buf0[0:96] -> buf1
    mfma_layer<96, 1>(wb + 12288, wb + 18432, b_m0, buf0, S0, buf1, S1,
                      (TS*)nullptr, 0, 0, wm, wn, lrow, lcol);
    __syncthreads();
    // L4: gelu(h @ W_m1 + b)            buf1 -> buf0[0:64]
    mfma_layer<64, 1>(wb + 24576, wb + 28672, b_m1, buf1, S1, buf0, S0,
                      (TS*)nullptr, 0, 0, wm, wn, lrow, lcol);
    __syncthreads();
    // L5: t = h @ Wc + bc -> global T
    mfma_layer<64, 2>(wb + 32768, wb + 36864, bc, buf0, S0, (ushort_t*)nullptr, 0,
                      Tout, nodebase, N, wm, wn, lrow, lcol);
}

// ---------------- per-graph reduction + Lcomb matmul ----------------
__device__ __forceinline__ float loadT(const float* p) { return *p; }
__device__ __forceinline__ float loadT(const ushort_t* p) { return bf2f(*p); }

template<typename TS>
__global__ __launch_bounds__(256)
void graph_kernel(const TS* __restrict__ Tin, const float* __restrict__ pos,
                  const int* __restrict__ seg, const float* __restrict__ Lcomb,
                  float* __restrict__ out, int G) {
    __shared__ float g1s[4][64][3];
    const int lane = threadIdx.x & 63;
    const int wid = threadIdx.x >> 6;
    const int g = blockIdx.x * 4 + wid;
    const bool active = g < G;

    if (active) {
        const int s = seg[g], e = seg[g + 1];
        float a0 = 0.f, a1 = 0.f, a2 = 0.f;
        for (int nn = s; nn < e; ++nn) {
            float t = loadT(Tin + (size_t)nn * 64 + lane);
            float qx = pos[3 * nn + 0], qy = pos[3 * nn + 1], qz = pos[3 * nn + 2];
            a0 = fmaf(t, qx, a0);
            a1 = fmaf(t, qy, a1);
            a2 = fmaf(t, qz, a2);
        }
        float cnt = (float)((e - s) > 0 ? (e - s) : 1);
        float sc = 1.7320508075688772f * 0.125f * (1.0f + 1.0f / cnt);
        g1s[wid][lane][0] = a0 * sc;
        g1s[wid][lane][1] = a1 * sc;
        g1s[wid][lane][2] = a2 * sc;
    }
    __syncthreads();
    if (!active) return;

    float o0 = 0.f, o1 = 0.f, o2 = 0.f, p0 = 0.f, p1 = 0.f, p2 = 0.f;
    const int v2 = 64 + lane;
    for (int u = 0; u < 64; ++u) {
        float b0 = g1s[wid][u][0], b1 = g1s[wid][u][1], b2 = g1s[wid][u][2];
        float l0 = Lcomb[u * 85 + lane];
        o0 = fmaf(b0, l0, o0); o1 = fmaf(b1, l0, o1); o2 = fmaf(b2, l0, o2);
        if (lane < 21) {
            float l1 = Lcomb[u * 85 + v2];
            p0 = fmaf(b0, l1, p0); p1 = fmaf(b1, l1, p1); p2 = fmaf(b2, l1, p2);
        }
    }
    float* og = out + (size_t)g * 255;
    og[3 * lane + 0] = o0; og[3 * lane + 1] = o1; og[3 * lane + 2] = o2;
    if (lane < 21) {
        og[3 * v2 + 0] = p0; og[3 * v2 + 1] = p1; og[3 * v2 + 2] = p2;
    }
}

extern "C" void kernel_launch(void* const* d_in, const int* in_sizes, int n_in,
                              void* d_out, int out_size, void* d_ws, size_t ws_size,
                              hipStream_t stream) {
    const float* pos        = (const float*)d_in[0];
    const int*   z          = (const int*)d_in[1];
    const int*   batch      = (const int*)d_in[2];
    const float* node_table = (const float*)d_in[3];
    const float* W_rbf0     = (const float*)d_in[4];
    const float* b_rbf0     = (const float*)d_in[5];
    const float* W_rbf1     = (const float*)d_in[6];
    const float* b_rbf1     = (const float*)d_in[7];
    const float* W_m0       = (const float*)d_in[8];
    const float* b_m0       = (const float*)d_in[9];
    const float* W_m1       = (const float*)d_in[10];
    const float* b_m1       = (const float*)d_in[11];
    const float* W_m2       = (const float*)d_in[12];
    const float* b_m2       = (const float*)d_in[13];
    const float* w_tp1      = (const float*)d_in[15];
    const float* L1o        = (const float*)d_in[18];
    const float* L_out      = (const float*)d_in[20];
    float* out = (float*)d_out;

    const int N = in_sizes[0] / 3;       // 200000
    const int G = out_size / 255;        // 8192

    char* ws = (char*)d_ws;
    float*    Wc    = (float*)(ws + 0);         // 16384
    float*    bc    = (float*)(ws + 16384);     // 256
    float*    Lcomb = (float*)(ws + 16640);     // 21760 -> 38400
    int*      seg   = (int*)(ws + 38400);       // 32772 -> 71172 (pad to 71424)
    ushort_t* wb    = (ushort_t*)(ws + 71424);  // 81920 -> 153344 (pad to 153600)
    const size_t toff = 153600;
    const size_t needF32 = toff + (size_t)N * 64 * sizeof(float);
    const bool useF32 = ws_size >= needF32;

    fold1_kernel<<<38, 256, 0, stream>>>(W_m2, b_m2, w_tp1, L1o, L_out, Wc, bc, Lcomb);
    fold2_kernel<<<40, 256, 0, stream>>>(W_rbf0, W_rbf1, W_m0, W_m1, Wc, wb);
    seg_kernel<<<(N + 255) / 256, 256, 0, stream>>>(batch, seg, N, G);

    const int nblocks = (N + 127) / 128;
    if (useF32) {
        float* T = (float*)(ws + toff);
        node_mfma_kernel<float><<<nblocks, 256, 0, stream>>>(
            pos, z, node_table, wb, b_rbf0, b_rbf1, b_m0, b_m1, bc, T, N);
        graph_kernel<float><<<(G + 3) / 4, 256, 0, stream>>>(T, pos, seg, Lcomb, out, G);
    } else {
        ushort_t* T = (ushort_t*)(ws + toff);
        node_mfma_kernel<ushort_t><<<nblocks, 256, 0, stream>>>(
            pos, z, node_table, wb, b_rbf0, b_rbf1, b_m0, b_m1, bc, T, N);
        graph_kernel<ushort_t><<<(G + 3) / 4, 256, 0, stream>>>(T, pos, seg, Lcomb, out, G);
    }
}

// Round 4
// 83.517 us; speedup vs baseline: 3.8151x; 1.1646x over previous
//
#include <hip/hip_runtime.h>

// Only the l=1 path reaches the output (g0/g2/c0/c2/w_tp0/w_tp2/L0/L2e are dead).
// t[i] = MLP(node i) @ (W_m2@w_tp1) + b_m2@w_tp1 ; enc = agg(segsum(t x sqrt3*pos)) @ (L1o@L_out)/64
// Node MLP on MFMA bf16, weights split hi+lo bf16 (error ~ f32). One wave per 64
// nodes, in-place LDS activations, barriers as intra-wave memory fences (cheap at 1 wave).

typedef __attribute__((ext_vector_type(8))) short bf16x8;
typedef __attribute__((ext_vector_type(4))) float f32x4;
typedef unsigned short ushort_t;

#define SB 104   // LDS row stride in ushorts: 96 cols + 8 pad

__device__ __forceinline__ unsigned rnebits(float x) {   // RNE-rounded, bf16 in top 16 bits
    unsigned u = __float_as_uint(x);
    return u + 0x7fffu + ((u >> 16) & 1u);
}
__device__ __forceinline__ ushort_t f2bf(float x) { return (ushort_t)(rnebits(x) >> 16); }
__device__ __forceinline__ float bf2f(ushort_t h) { return __uint_as_float(((unsigned)h) << 16); }
__device__ __forceinline__ unsigned pack2bf(float lo, float hi) {   // lo -> low halfword
    return (rnebits(hi) & 0xffff0000u) | (rnebits(lo) >> 16);
}

// gelu(x) = x - x * rcp(exp2(x*(C + Ca*x^2)) + 1);  C = 2*0.79788456*log2(e)
__device__ __forceinline__ float gelu(float x) {
    float x2 = x * x;
    float y  = x * fmaf(0.10294324f, x2, 2.3022082f);
    float e  = __builtin_amdgcn_exp2f(y);
    float r  = __builtin_amdgcn_rcpf(e + 1.0f);
    return fmaf(-x, r, x);
}

// ---------------- prep: fold weights (hi/lo bf16, transposed) + seg boundaries ----------------
// wb layout ([feat][K] row-major, ushort offsets):
//  W_rbf0 hi 0 / lo 2048 | W_rbf1 hi 4096 / lo 8192 | W_m0 hi 12288 / lo 18432
//  W_m1 hi 24576 / lo 28672 | Wc hi 32768 / lo 36864   (end 40960)
__global__ __launch_bounds__(256)
void prep_kernel(const float* __restrict__ W_rbf0, const float* __restrict__ W_rbf1,
                 const float* __restrict__ W_m0, const float* __restrict__ W_m1,
                 const float* __restrict__ W_m2, const float* __restrict__ b_m2,
                 const float* __restrict__ w_tp1,
                 const float* __restrict__ L1o, const float* __restrict__ L_out,
                 const int* __restrict__ batch,
                 ushort_t* __restrict__ wb, float* __restrict__ bc,
                 float* __restrict__ Lcomb, int* __restrict__ seg, int N, int G)
{
    if (blockIdx.x >= 102) {   // ---- seg part ----
        int i = (blockIdx.x - 102) * 256 + threadIdx.x;
        if (i >= N) return;
        int bi = batch[i];
        int bprev = (i == 0) ? -1 : batch[i - 1];
        for (int g = bprev + 1; g <= bi; ++g) seg[g] = i;
        if (i == N - 1) for (int g = bi + 1; g <= G; ++g) seg[g] = N;
        return;
    }
    int idx = blockIdx.x * 256 + threadIdx.x;   // fold part, 25984 items
    float w;
    ushort_t *dh, *dl;
    if (idx < 2048) {                    // W_rbf0 [f][32]
        int f = idx >> 5, k = idx & 31;
        w = W_rbf0[k * 64 + f]; dh = wb + idx; dl = wb + 2048 + idx;
    } else if (idx < 6144) {             // W_rbf1 [f][64]
        int j = idx - 2048, f = j >> 6, k = j & 63;
        w = W_rbf1[k * 64 + f]; dh = wb + 4096 + j; dl = wb + 8192 + j;
    } else if (idx < 12288) {            // W_m0 [f][96]
        int j = idx - 6144, f = j / 96, k = j - 96 * f;
        w = W_m0[k * 64 + f]; dh = wb + 12288 + j; dl = wb + 18432 + j;
    } else if (idx < 16384) {            // W_m1 [f][64]
        int j = idx - 12288, f = j >> 6, k = j & 63;
        w = W_m1[k * 64 + f]; dh = wb + 24576 + j; dl = wb + 28672 + j;
    } else if (idx < 20480) {            // Wc[f=t_out][k=h_in] = sum_j W_m2[k][j]*w_tp1[j][f]
        int j = idx - 16384, f = j >> 6, k = j & 63;
        float s = 0.f;
        for (int jj = 0; jj < 64; ++jj) s = fmaf(W_m2[k * 64 + jj], w_tp1[jj * 64 + f], s);
        w = s; dh = wb + 32768 + j; dl = wb + 36864 + j;
    } else if (idx < 20544) {            // bc
        int b = idx - 20480;
        float s = 0.f;
        for (int k = 0; k < 64; ++k) s = fmaf(b_m2[k], w_tp1[k * 64 + b], s);
        bc[b] = s;
        return;
    } else if (idx < 25984) {            // Lcomb = (L1o@L_out)/64
        int j = idx - 20544, u = j / 85, v = j - 85 * u;
        float s = 0.f;
        for (int k = 0; k < 64; ++k) s = fmaf(L1o[u * 64 + k], L_out[k * 85 + v], s);
        Lcomb[j] = 0.015625f * s;
        return;
    } else return;
    ushort_t h = f2bf(w);
    *dh = h;
    *dl = f2bf(w - bf2f(h));
}

// ---------------- node MLP: one wave = 64 nodes ----------------
// One dense layer, in-place. ACT: 0 none->LDS, 1 gelu->LDS, 2 none->global bf16 T.
template<int KT, int ACT>
__device__ __forceinline__ void layer64(
    const ushort_t* __restrict__ Wh, const ushort_t* __restrict__ Wl,
    const float* __restrict__ bias, ushort_t* buf,
    ushort_t* __restrict__ Tout, int nodebase, int N, int lrow, int lcol)
{
    constexpr int K = KT * 32;
    __syncthreads();   // fence: previous layer's LDS writes visible/ordered
    // hoist ALL B-fragments to registers before any in-place write
    bf16x8 bb[4][KT];
    #pragma unroll
    for (int n = 0; n < 4; ++n)
        #pragma unroll
        for (int kt = 0; kt < KT; ++kt)
            bb[n][kt] = *(const bf16x8*)&buf[(n * 16 + lcol) * SB + kt * 32 + lrow * 8];
    __syncthreads();   // fence: no epilogue store may sink above the hoist loads
    #pragma unroll
    for (int m = 0; m < 4; ++m) {
        const int f0 = m * 16 + lrow * 4;
        float4 bv = *(const float4*)(bias + f0);
        f32x4 acc[4];
        #pragma unroll
        for (int n = 0; n < 4; ++n) { acc[n][0] = bv.x; acc[n][1] = bv.y; acc[n][2] = bv.z; acc[n][3] = bv.w; }
        #pragma unroll
        for (int kt = 0; kt < KT; ++kt) {
            bf16x8 ah = *(const bf16x8*)(Wh + (m * 16 + lcol) * K + kt * 32 + lrow * 8);
            bf16x8 al = *(const bf16x8*)(Wl + (m * 16 + lcol) * K + kt * 32 + lrow * 8);
            #pragma unroll
            for (int n = 0; n < 4; ++n) {
                acc[n] = __builtin_amdgcn_mfma_f32_16x16x32_bf16(ah, bb[n][kt], acc[n], 0, 0, 0);
                acc[n] = __builtin_amdgcn_mfma_f32_16x16x32_bf16(al, bb[n][kt], acc[n], 0, 0, 0);
            }
        }
        #pragma unroll
        for (int n = 0; n < 4; ++n) {
            f32x4 v = acc[n];
            if (ACT == 1) {
                #pragma unroll
                for (int r = 0; r < 4; ++r) v[r] = gelu(v[r]);
            }
            uint2 pk;
            pk.x = pack2bf(v[0], v[1]);
            pk.y = pack2bf(v[2], v[3]);
            if (ACT == 2) {
                const int node = nodebase + n * 16 + lcol;
                if (node < N) *(uint2*)(Tout + (size_t)node * 64 + f0) = pk;
            } else {
                *(uint2*)&buf[(n * 16 + lcol) * SB + f0] = pk;
            }
        }
    }
}

__global__ __launch_bounds__(64, 3)
void node_mfma_kernel(const float* __restrict__ pos, const int* __restrict__ z,
                      const float* __restrict__ node_table,
                      const ushort_t* __restrict__ wb,
                      const float* __restrict__ b_rbf0, const float* __restrict__ b_rbf1,
                      const float* __restrict__ b_m0, const float* __restrict__ b_m1,
                      const float* __restrict__ bc,
                      ushort_t* __restrict__ Tout, int N)
{
    __shared__ ushort_t buf[64 * SB];   // 13312 B -> 12 waves/CU
    const int lane = threadIdx.x;
    const int nodebase = blockIdx.x * 64;
    int gn = nodebase + lane;
    if (gn >= N) gn = N - 1;

    // stage rbf (cols 0..31) and table (cols 64..95); each lane writes its own row
    const float px = pos[3 * gn], py = pos[3 * gn + 1], pz = pos[3 * gn + 2];
    const float dist = sqrtf(px * px + py * py + pz * pz);
    {
        unsigned rb[16];
        #pragma unroll
        for (int j = 0; j < 16; ++j) {
            float d0 = dist - (float)(2 * j)     * (1.0f / 31.0f);
            float d1 = dist - (float)(2 * j + 1) * (1.0f / 31.0f);
            rb[j] = pack2bf(__builtin_amdgcn_exp2f(-693.2149671554846f * d0 * d0),
                            __builtin_amdgcn_exp2f(-693.2149671554846f * d1 * d1));
        }
        uint4* dst = (uint4*)&buf[lane * SB];
        dst[0] = make_uint4(rb[0], rb[1], rb[2], rb[3]);
        dst[1] = make_uint4(rb[4], rb[5], rb[6], rb[7]);
        dst[2] = make_uint4(rb[8], rb[9], rb[10], rb[11]);
        dst[3] = make_uint4(rb[12], rb[13], rb[14], rb[15]);
    }
    {
        const float* tb = node_table + (size_t)z[gn] * 32;
        unsigned tl[16];
        #pragma unroll
        for (int j = 0; j < 8; ++j) {
            float4 tv = *(const float4*)(tb + 4 * j);
            tl[2 * j]     = pack2bf(tv.x, tv.y);
            tl[2 * j + 1] = pack2bf(tv.z, tv.w);
        }
        uint4* dst = (uint4*)&buf[lane * SB + 64];
        dst[0] = make_uint4(tl[0], tl[1], tl[2], tl[3]);
        dst[1] = make_uint4(tl[4], tl[5], tl[6], tl[7]);
        dst[2] = make_uint4(tl[8], tl[9], tl[10], tl[11]);
        dst[3] = make_uint4(tl[12], tl[13], tl[14], tl[15]);
    }

    const int lrow = lane >> 4, lcol = lane & 15;
    layer64<1, 1>(wb + 0,     wb + 2048,  b_rbf0, buf, (ushort_t*)nullptr, 0, 0, lrow, lcol);
    layer64<2, 0>(wb + 4096,  wb + 8192,  b_rbf1, buf, (ushort_t*)nullptr, 0, 0, lrow, lcol);
    layer64<3, 1>(wb + 12288, wb + 18432, b_m0,   buf, (ushort_t*)nullptr, 0, 0, lrow, lcol);
    layer64<2, 1>(wb + 24576, wb + 28672, b_m1,   buf, (ushort_t*)nullptr, 0, 0, lrow, lcol);
    layer64<2, 2>(wb + 32768, wb + 36864, bc,     buf, Tout, nodebase, N, lrow, lcol);
}

// ---------------- per-graph reduction + Lcomb matmul ----------------
__global__ __launch_bounds__(256)
void graph_kernel(const ushort_t* __restrict__ Tin, const float* __restrict__ pos,
                  const int* __restrict__ seg, const float* __restrict__ Lcomb,
                  float* __restrict__ out, int G) {
    __shared__ float g1s[4][64][3];
    const int lane = threadIdx.x & 63;
    const int wid = threadIdx.x >> 6;
    const int g = blockIdx.x * 4 + wid;
    const bool active = g < G;

    if (active) {
        const int s = seg[g], e = seg[g + 1];
        float a0 = 0.f, a1 = 0.f, a2 = 0.f;
        for (int nn = s; nn < e; ++nn) {
            float t = bf2f(Tin[(size_t)nn * 64 + lane]);   // coalesced 128B/wave
            float qx = pos[3 * nn + 0], qy = pos[3 * nn + 1], qz = pos[3 * nn + 2];
            a0 = fmaf(t, qx, a0);
            a1 = fmaf(t, qy, a1);
            a2 = fmaf(t, qz, a2);
        }
        float cnt = (float)((e - s) > 0 ? (e - s) : 1);
        float sc = 1.7320508075688772f * 0.125f * (1.0f + 1.0f / cnt);
        g1s[wid][lane][0] = a0 * sc;
        g1s[wid][lane][1] = a1 * sc;
        g1s[wid][lane][2] = a2 * sc;
    }
    __syncthreads();
    if (!active) return;

    float o0 = 0.f, o1 = 0.f, o2 = 0.f, p0 = 0.f, p1 = 0.f, p2 = 0.f;
    const int v2 = 64 + lane;
    for (int u = 0; u < 64; ++u) {
        float b0 = g1s[wid][u][0], b1 = g1s[wid][u][1], b2 = g1s[wid][u][2];
        float l0 = Lcomb[u * 85 + lane];
        o0 = fmaf(b0, l0, o0); o1 = fmaf(b1, l0, o1); o2 = fmaf(b2, l0, o2);
        if (lane < 21) {
            float l1 = Lcomb[u * 85 + v2];
            p0 = fmaf(b0, l1, p0); p1 = fmaf(b1, l1, p1); p2 = fmaf(b2, l1, p2);
        }
    }
    float* og = out + (size_t)g * 255;
    og[3 * lane + 0] = o0; og[3 * lane + 1] = o1; og[3 * lane + 2] = o2;
    if (lane < 21) {
        og[3 * v2 + 0] = p0; og[3 * v2 + 1] = p1; og[3 * v2 + 2] = p2;
    }
}

extern "C" void kernel_launch(void* const* d_in, const int* in_sizes, int n_in,
                              void* d_out, int out_size, void* d_ws, size_t ws_size,
                              hipStream_t stream) {
    const float* pos        = (const float*)d_in[0];
    const int*   z          = (const int*)d_in[1];
    const int*   batch      = (const int*)d_in[2];
    const float* node_table = (const float*)d_in[3];
    const float* W_rbf0     = (const float*)d_in[4];
    const float* b_rbf0     = (const float*)d_in[5];
    const float* W_rbf1     = (const float*)d_in[6];
    const float* b_rbf1     = (const float*)d_in[7];
    const float* W_m0       = (const float*)d_in[8];
    const float* b_m0       = (const float*)d_in[9];
    const float* W_m1       = (const float*)d_in[10];
    const float* b_m1       = (const float*)d_in[11];
    const float* W_m2       = (const float*)d_in[12];
    const float* b_m2       = (const float*)d_in[13];
    const float* w_tp1      = (const float*)d_in[15];
    const float* L1o        = (const float*)d_in[18];
    const float* L_out      = (const float*)d_in[20];
    float* out = (float*)d_out;

    const int N = in_sizes[0] / 3;       // 200000
    const int G = out_size / 255;        // 8192

    char* ws = (char*)d_ws;
    float*    bc    = (float*)(ws + 0);          // 256 B
    float*    Lcomb = (float*)(ws + 256);        // 21760 -> 22016, pad 22528
    int*      seg   = (int*)(ws + 22528);        // 32772 -> 55300, pad 55424
    ushort_t* wb    = (ushort_t*)(ws + 55424);   // 81920 -> 137344, pad 137472
    ushort_t* T     = (ushort_t*)(ws + 137472);  // N*64*2 = 25.6 MB

    const int segBlocks = (N + 255) / 256;
    prep_kernel<<<102 + segBlocks, 256, 0, stream>>>(
        W_rbf0, W_rbf1, W_m0, W_m1, W_m2, b_m2, w_tp1, L1o, L_out,
        batch, wb, bc, Lcomb, seg, N, G);

    node_mfma_kernel<<<(N + 63) / 64, 64, 0, stream>>>(
        pos, z, node_table, wb, b_rbf0, b_rbf1, b_m0, b_m1, bc, T, N);

    graph_kernel<<<(G + 3) / 4, 256, 0, stream>>>(T, pos, seg, Lcomb, out, G);
}

// Round 5
// 81.628 us; speedup vs baseline: 3.9034x; 1.0231x over previous
//
#include <hip/hip_runtime.h>

// Only the l=1 path reaches the output (g0/g2/c0/c2/w_tp0/w_tp2/L0/L2e are dead).
// t[i] = MLP(node i) @ (W_m2@w_tp1) + b_m2@w_tp1 ; enc = agg(segsum(t x sqrt3*pos)) @ (L1o@L_out)/64
// Node MLP on MFMA bf16, weights split hi+lo bf16 (error ~ f32). One wave = 64 nodes,
// ping-pong LDS buffers, zero barriers (per-wave in-order DS + lgkm fences only).

typedef __attribute__((ext_vector_type(8))) short bf16x8;
typedef __attribute__((ext_vector_type(4))) float f32x4;
typedef unsigned short ushort_t;

#define SBW 72   // LDS row stride in ushorts: 64 cols + 8 pad (16B-aligned rows, 2-way max alias)

__device__ __forceinline__ unsigned rnebits(float x) {   // RNE-rounded, bf16 in top 16 bits
    unsigned u = __float_as_uint(x);
    return u + 0x7fffu + ((u >> 16) & 1u);
}
__device__ __forceinline__ ushort_t f2bf(float x) { return (ushort_t)(rnebits(x) >> 16); }
__device__ __forceinline__ float bf2f(ushort_t h) { return __uint_as_float(((unsigned)h) << 16); }
__device__ __forceinline__ unsigned pack2bf(float lo, float hi) {   // lo -> low halfword
    return (rnebits(hi) & 0xffff0000u) | (rnebits(lo) >> 16);
}
__device__ __forceinline__ void lds_fence() {
    asm volatile("s_waitcnt lgkmcnt(0)" ::: "memory");
    __builtin_amdgcn_sched_barrier(0);
}

// gelu(x) = x - x * rcp(exp2(x*(C + Ca*x^2)) + 1);  C = 2*0.79788456*log2(e)
__device__ __forceinline__ float gelu(float x) {
    float x2 = x * x;
    float y  = x * fmaf(0.10294324f, x2, 2.3022082f);
    float e  = __builtin_amdgcn_exp2f(y);
    float r  = __builtin_amdgcn_rcpf(e + 1.0f);
    return fmaf(-x, r, x);
}

// ---------------- prep: fold weights (hi/lo bf16, transposed) + table bf16 + seg ----------------
// wb layout ([feat][K] row-major, ushort offsets):
//  W_rbf0 hi 0 / lo 2048 | W_rbf1 hi 4096 / lo 8192 | W_m0 hi 12288 / lo 18432
//  W_m1 hi 24576 / lo 28672 | Wc hi 32768 / lo 36864 | table_bf16 40960 (100x32) | end 44160
__global__ __launch_bounds__(256)
void prep_kernel(const float* __restrict__ W_rbf0, const float* __restrict__ W_rbf1,
                 const float* __restrict__ W_m0, const float* __restrict__ W_m1,
                 const float* __restrict__ W_m2, const float* __restrict__ b_m2,
                 const float* __restrict__ w_tp1,
                 const float* __restrict__ L1o, const float* __restrict__ L_out,
                 const float* __restrict__ node_table, const int* __restrict__ batch,
                 ushort_t* __restrict__ wb, float* __restrict__ bc,
                 float* __restrict__ Lcomb, int* __restrict__ seg, int N, int G)
{
    if (blockIdx.x >= 115) {   // ---- seg part ----
        int i = (blockIdx.x - 115) * 256 + threadIdx.x;
        if (i >= N) return;
        int bi = batch[i];
        int bprev = (i == 0) ? -1 : batch[i - 1];
        for (int g = bprev + 1; g <= bi; ++g) seg[g] = i;
        if (i == N - 1) for (int g = bi + 1; g <= G; ++g) seg[g] = N;
        return;
    }
    int idx = blockIdx.x * 256 + threadIdx.x;   // fold part, 29184 items
    float w;
    ushort_t *dh, *dl;
    if (idx < 2048) {                    // W_rbf0 [f][32]
        int f = idx >> 5, k = idx & 31;
        w = W_rbf0[k * 64 + f]; dh = wb + idx; dl = wb + 2048 + idx;
    } else if (idx < 6144) {             // W_rbf1 [f][64]
        int j = idx - 2048, f = j >> 6, k = j & 63;
        w = W_rbf1[k * 64 + f]; dh = wb + 4096 + j; dl = wb + 8192 + j;
    } else if (idx < 12288) {            // W_m0 [f][96]
        int j = idx - 6144, f = j / 96, k = j - 96 * f;
        w = W_m0[k * 64 + f]; dh = wb + 12288 + j; dl = wb + 18432 + j;
    } else if (idx < 16384) {            // W_m1 [f][64]
        int j = idx - 12288, f = j >> 6, k = j & 63;
        w = W_m1[k * 64 + f]; dh = wb + 24576 + j; dl = wb + 28672 + j;
    } else if (idx < 20480) {            // Wc[f=t_out][k=h_in] = sum_j W_m2[k][j]*w_tp1[j][f]
        int j = idx - 16384, f = j >> 6, k = j & 63;
        float s = 0.f;
        for (int jj = 0; jj < 64; ++jj) s = fmaf(W_m2[k * 64 + jj], w_tp1[jj * 64 + f], s);
        w = s; dh = wb + 32768 + j; dl = wb + 36864 + j;
    } else if (idx < 20544) {            // bc
        int b = idx - 20480;
        float s = 0.f;
        for (int k = 0; k < 64; ++k) s = fmaf(b_m2[k], w_tp1[k * 64 + b], s);
        bc[b] = s;
        return;
    } else if (idx < 25984) {            // Lcomb = (L1o@L_out)/64
        int j = idx - 20544, u = j / 85, v = j - 85 * u;
        float s = 0.f;
        for (int k = 0; k < 64; ++k) s = fmaf(L1o[u * 64 + k], L_out[k * 85 + v], s);
        Lcomb[j] = 0.015625f * s;
        return;
    } else if (idx < 29184) {            // node_table -> bf16 [100][32]
        int j = idx - 25984;
        wb[40960 + j] = f2bf(node_table[j]);
        return;
    } else return;
    ushort_t h = f2bf(w);
    *dh = h;
    *dl = f2bf(w - bf2f(h));
}

// ---------------- one dense layer on MFMA ----------------
// kt-outer, acc[4][4] live: each B-fragment read once from LDS.
// TABLE: append k=64..95 slice gathered from bf16 node_table (global, L1-hot).
// ACT: 0 none, 1 gelu. Output packed bf16 -> dst (LDS).
template<int KT, int ACT, bool TABLE>
__device__ __forceinline__ void layerX(
    const ushort_t* __restrict__ Wh, const ushort_t* __restrict__ Wl,
    const float* __restrict__ bias,
    const ushort_t* src, ushort_t* dst,
    const ushort_t* __restrict__ tab_bf, const int* __restrict__ zp,
    int nodebase, int N, int lrow, int lcol)
{
    constexpr int K = TABLE ? (KT * 32 + 32) : (KT * 32);
    f32x4 acc[4][4];
    #pragma unroll
    for (int m = 0; m < 4; ++m) {
        float4 bv = *(const float4*)(bias + m * 16 + lrow * 4);
        #pragma unroll
        for (int n = 0; n < 4; ++n) {
            acc[m][n][0] = bv.x; acc[m][n][1] = bv.y; acc[m][n][2] = bv.z; acc[m][n][3] = bv.w;
        }
    }
    #pragma unroll
    for (int kt = 0; kt < KT; ++kt) {
        const int kof = kt * 32 + lrow * 8;
        bf16x8 bb[4];
        #pragma unroll
        for (int n = 0; n < 4; ++n)
            bb[n] = *(const bf16x8*)&src[(n * 16 + lcol) * SBW + kof];
        #pragma unroll
        for (int m = 0; m < 4; ++m) {
            bf16x8 ah = *(const bf16x8*)(Wh + (m * 16 + lcol) * K + kof);
            bf16x8 al = *(const bf16x8*)(Wl + (m * 16 + lcol) * K + kof);
            #pragma unroll
            for (int n = 0; n < 4; ++n) {
                acc[m][n] = __builtin_amdgcn_mfma_f32_16x16x32_bf16(ah, bb[n], acc[m][n], 0, 0, 0);
                acc[m][n] = __builtin_amdgcn_mfma_f32_16x16x32_bf16(al, bb[n], acc[m][n], 0, 0, 0);
            }
        }
    }
    if (TABLE) {
        const int kof = KT * 32 + lrow * 8;
        bf16x8 bb[4];
        #pragma unroll
        for (int n = 0; n < 4; ++n) {
            int node = nodebase + n * 16 + lcol;
            if (node > N - 1) node = N - 1;
            bb[n] = *(const bf16x8*)(tab_bf + zp[node] * 32 + lrow * 8);
        }
        #pragma unroll
        for (int m = 0; m < 4; ++m) {
            bf16x8 ah = *(const bf16x8*)(Wh + (m * 16 + lcol) * K + kof);
            bf16x8 al = *(const bf16x8*)(Wl + (m * 16 + lcol) * K + kof);
            #pragma unroll
            for (int n = 0; n < 4; ++n) {
                acc[m][n] = __builtin_amdgcn_mfma_f32_16x16x32_bf16(ah, bb[n], acc[m][n], 0, 0, 0);
                acc[m][n] = __builtin_amdgcn_mfma_f32_16x16x32_bf16(al, bb[n], acc[m][n], 0, 0, 0);
            }
        }
    }
    #pragma unroll
    for (int m = 0; m < 4; ++m) {
        const int f0 = m * 16 + lrow * 4;
        #pragma unroll
        for (int n = 0; n < 4; ++n) {
            f32x4 v = acc[m][n];
            if (ACT == 1) {
                #pragma unroll
                for (int r = 0; r < 4; ++r) v[r] = gelu(v[r]);
            }
            uint2 pk;
            pk.x = pack2bf(v[0], v[1]);
            pk.y = pack2bf(v[2], v[3]);
            *(uint2*)&dst[(n * 16 + lcol) * SBW + f0] = pk;
        }
    }
}

__global__ __launch_bounds__(64, 2)
void node_mfma_kernel(const float* __restrict__ pos, const int* __restrict__ z,
                      const ushort_t* __restrict__ wb,
                      const float* __restrict__ b_rbf0, const float* __restrict__ b_rbf1,
                      const float* __restrict__ b_m0, const float* __restrict__ b_m1,
                      const float* __restrict__ bc,
                      ushort_t* __restrict__ Tout, int N)
{
    __shared__ ushort_t bufA[64 * SBW];   // 9216 B
    __shared__ ushort_t bufB[64 * SBW];   // 9216 B  -> 18432 total -> 8 blocks/CU
    const int lane = threadIdx.x;
    const int nodebase = blockIdx.x * 64;
    int gn = nodebase + lane;
    if (gn >= N) gn = N - 1;
    const ushort_t* tab_bf = wb + 40960;

    // stage rbf (32 cols) into bufA row `lane`
    {
        const float px = pos[3 * gn], py = pos[3 * gn + 1], pz = pos[3 * gn + 2];
        const float dist = sqrtf(px * px + py * py + pz * pz);
        unsigned rb[16];
        #pragma unroll
        for (int j = 0; j < 16; ++j) {
            float d0 = dist - (float)(2 * j)     * (1.0f / 31.0f);
            float d1 = dist - (float)(2 * j + 1) * (1.0f / 31.0f);
            rb[j] = pack2bf(__builtin_amdgcn_exp2f(-693.2149671554846f * d0 * d0),
                            __builtin_amdgcn_exp2f(-693.2149671554846f * d1 * d1));
        }
        uint4* dst = (uint4*)&bufA[lane * SBW];
        dst[0] = make_uint4(rb[0], rb[1], rb[2], rb[3]);
        dst[1] = make_uint4(rb[4], rb[5], rb[6], rb[7]);
        dst[2] = make_uint4(rb[8], rb[9], rb[10], rb[11]);
        dst[3] = make_uint4(rb[12], rb[13], rb[14], rb[15]);
    }
    lds_fence();

    const int lrow = lane >> 4, lcol = lane & 15;
    // L1: gelu(rbf @ W_rbf0 + b)        A -> B   (K=32)
    layerX<1, 1, false>(wb + 0, wb + 2048, b_rbf0, bufA, bufB, tab_bf, z, nodebase, N, lrow, lcol);
    lds_fence();
    // L2: r @ W_rbf1 + b (no act)       B -> A   (K=64)
    layerX<2, 0, false>(wb + 4096, wb + 8192, b_rbf1, bufB, bufA, tab_bf, z, nodebase, N, lrow, lcol);
    lds_fence();
    // L3: gelu([r|table] @ W_m0 + b)    A (+table gather) -> B   (K=96)
    layerX<2, 1, true>(wb + 12288, wb + 18432, b_m0, bufA, bufB, tab_bf, z, nodebase, N, lrow, lcol);
    lds_fence();
    // L4: gelu(h @ W_m1 + b)            B -> A   (K=64)
    layerX<2, 1, false>(wb + 24576, wb + 28672, b_m1, bufB, bufA, tab_bf, z, nodebase, N, lrow, lcol);
    lds_fence();
    // L5: t = h @ Wc + bc               A -> B   (K=64)
    layerX<2, 0, false>(wb + 32768, wb + 36864, bc, bufA, bufB, tab_bf, z, nodebase, N, lrow, lcol);
    lds_fence();

    // stream the 64x64 bf16 tile out fully coalesced (8 x 1KB stores)
    {
        ushort_t* tb = Tout + (size_t)nodebase * 64;
        #pragma unroll
        for (int i = 0; i < 8; ++i) {
            bf16x8 v = *(const bf16x8*)&bufB[(i * 8 + (lane >> 3)) * SBW + (lane & 7) * 8];
            *(bf16x8*)(tb + i * 512 + lane * 8) = v;
        }
    }
}

// ---------------- per-graph reduction + Lcomb matmul ----------------
__global__ __launch_bounds__(256)
void graph_kernel(const ushort_t* __restrict__ Tin, const float* __restrict__ pos,
                  const int* __restrict__ seg, const float* __restrict__ Lcomb,
                  float* __restrict__ out, int G) {
    __shared__ float g1s[4][64][3];
    const int lane = threadIdx.x & 63;
    const int wid = threadIdx.x >> 6;
    const int g = blockIdx.x * 4 + wid;
    const bool active = g < G;

    if (active) {
        const int s = seg[g], e = seg[g + 1];
        float a0 = 0.f, a1 = 0.f, a2 = 0.f;
        for (int nn = s; nn < e; ++nn) {
            float t = bf2f(Tin[(size_t)nn * 64 + lane]);   // coalesced 128B/wave
            float qx = pos[3 * nn + 0], qy = pos[3 * nn + 1], qz = pos[3 * nn + 2];
            a0 = fmaf(t, qx, a0);
            a1 = fmaf(t, qy, a1);
            a2 = fmaf(t, qz, a2);
        }
        float cnt = (float)((e - s) > 0 ? (e - s) : 1);
        float sc = 1.7320508075688772f * 0.125f * (1.0f + 1.0f / cnt);
        g1s[wid][lane][0] = a0 * sc;
        g1s[wid][lane][1] = a1 * sc;
        g1s[wid][lane][2] = a2 * sc;
    }
    __syncthreads();
    if (!active) return;

    float o0 = 0.f, o1 = 0.f, o2 = 0.f, p0 = 0.f, p1 = 0.f, p2 = 0.f;
    const int v2 = 64 + lane;
    for (int u = 0; u < 64; ++u) {
        float b0 = g1s[wid][u][0], b1 = g1s[wid][u][1], b2 = g1s[wid][u][2];
        float l0 = Lcomb[u * 85 + lane];
        o0 = fmaf(b0, l0, o0); o1 = fmaf(b1, l0, o1); o2 = fmaf(b2, l0, o2);
        if (lane < 21) {
            float l1 = Lcomb[u * 85 + v2];
            p0 = fmaf(b0, l1, p0); p1 = fmaf(b1, l1, p1); p2 = fmaf(b2, l1, p2);
        }
    }
    float* og = out + (size_t)g * 255;
    og[3 * lane + 0] = o0; og[3 * lane + 1] = o1; og[3 * lane + 2] = o2;
    if (lane < 21) {
        og[3 * v2 + 0] = p0; og[3 * v2 + 1] = p1; og[3 * v2 + 2] = p2;
    }
}

extern "C" void kernel_launch(void* const* d_in, const int* in_sizes, int n_in,
                              void* d_out, int out_size, void* d_ws, size_t ws_size,
                              hipStream_t stream) {
    const float* pos        = (const float*)d_in[0];
    const int*   z          = (const int*)d_in[1];
    const int*   batch      = (const int*)d_in[2];
    const float* node_table = (const float*)d_in[3];
    const float* W_rbf0     = (const float*)d_in[4];
    const float* b_rbf0     = (const float*)d_in[5];
    const float* W_rbf1     = (const float*)d_in[6];
    const float* b_rbf1     = (const float*)d_in[7];
    const float* W_m0       = (const float*)d_in[8];
    const float* b_m0       = (const float*)d_in[9];
    const float* W_m1       = (const float*)d_in[10];
    const float* b_m1       = (const float*)d_in[11];
    const float* W_m2       = (const float*)d_in[12];
    const float* b_m2       = (const float*)d_in[13];
    const float* w_tp1      = (const float*)d_in[15];
    const float* L1o        = (const float*)d_in[18];
    const float* L_out      = (const float*)d_in[20];
    float* out = (float*)d_out;

    const int N = in_sizes[0] / 3;       // 200000
    const int G = out_size / 255;        // 8192

    char* ws = (char*)d_ws;
    float*    bc    = (float*)(ws + 0);          // 256 B
    float*    Lcomb = (float*)(ws + 256);        // 21760 -> 22016, pad 22528
    int*      seg   = (int*)(ws + 22528);        // 32772 -> 55300, pad 55552
    ushort_t* wb    = (ushort_t*)(ws + 55552);   // 44160 ush = 88320 B -> 143872, pad 144128
    ushort_t* T     = (ushort_t*)(ws + 144128);  // ceil(N/64)*64*64*2 = 25.6 MB

    const int segBlocks = (N + 255) / 256;
    prep_kernel<<<115 + segBlocks, 256, 0, stream>>>(
        W_rbf0, W_rbf1, W_m0, W_m1, W_m2, b_m2, w_tp1, L1o, L_out,
        node_table, batch, wb, bc, Lcomb, seg, N, G);

    node_mfma_kernel<<<(N + 63) / 64, 64, 0, stream>>>(
        pos, z, wb, b_rbf0, b_rbf1, b_m0, b_m1, bc, T, N);

    graph_kernel<<<(G + 3) / 4, 256, 0, stream>>>(T, pos, seg, Lcomb, out, G);
}